// Round 15
// baseline (78.343 us; speedup 1.0000x reference)
//
#include <hip/hip_runtime.h>

#define HSIZE 2048          // d-histogram buckets; packed lo16=pixel reps, hi16=points (n<32768)
#define CSH   6             // cell shift (64 px cells)
#define CSZ   64
#define NCG   4096          // global cell-array capacity
#define NCLDS 2048          // LDS cell capacity (this family: 34x60 = 2040)
#define BLP   10176         // build LDS point capacity
#define QLP   10176         // query LDS point capacity (81408 B)
#define TPP   16            // threads per point
#define TPB   640           // 40 pts/block -> 250 blocks (one round over 256 CUs)

// ---------------- K1: build (single workgroup) ----------------
// zero hist+done; counting-sort points into cells (ppk/sidx); gcell = {off, maxbits};
// pbr = pixelmax | rep<<31; meta = {RMAX, NCX, NCY}
__global__ __launch_bounds__(1024) void build_k(
    const int* __restrict__ kp, const float* __restrict__ sc,
    const int* __restrict__ nret_, const int* __restrict__ rows_, const int* __restrict__ cols_,
    int n, int* __restrict__ hist, int* __restrict__ meta, int* __restrict__ done,
    int2* __restrict__ gcell, int2* __restrict__ ppk, int* __restrict__ sidx,
    int* __restrict__ pbr, int* __restrict__ gscr) {
    __shared__ int2 lppL[BLP];
    __shared__ unsigned short sidxL[BLP];
    __shared__ int cnt[NCLDS];
    __shared__ int off_[NCLDS];
    __shared__ int cmx[NCLDS];
    __shared__ int wsum[8];
    int t = threadIdx.x, lane = t & 63, w = t >> 6;
    int rows = rows_[0], cols = cols_[0];
    int NCX = (cols + CSZ - 1) >> CSH;
    int NCY = (rows + CSZ - 1) >> CSH;
    int NC = NCX * NCY;
    bool fits = (NC <= NCLDS) && (n <= BLP);
    const int4* kp4 = (const int4*)kp;

    for (int i = t; i < HSIZE; i += 1024) hist[i] = 0;
    if (t == 0) done[0] = 0;

    if (fits) {
        for (int i = t; i < NCLDS; i += 1024) { cnt[i] = 0; cmx[i] = 0; }
        __syncthreads();
        for (int i = t; i < n; i += 1024) {
            int4 k = kp4[i];
            int c = (k.z >> CSH) * NCX + (k.w >> CSH);
            atomicAdd(&cnt[c], 1);
            atomicMax(&cmx[c], __float_as_int(sc[i]));   // scores > 0: bit order == value order
        }
        __syncthreads();
        // exclusive scan over NCLDS=2048: first 512 threads, 4 cells each, shfl scans
        int s4 = 0, l0 = 0, l1 = 0, l2 = 0, l3 = 0, x = 0;
        if (t < 512) {
            int b = t * 4;
            l0 = cnt[b]; l1 = cnt[b + 1]; l2 = cnt[b + 2]; l3 = cnt[b + 3];
            s4 = l0 + l1 + l2 + l3;
            x = s4;
            for (int o = 1; o < 64; o <<= 1) { int v = __shfl_up(x, o); if (lane >= o) x += v; }
            if (lane == 63) wsum[w] = x;
        }
        __syncthreads();
        if (w == 0) {
            int v = (lane < 8) ? wsum[lane] : 0;
            for (int o = 1; o < 8; o <<= 1) { int u = __shfl_up(v, o); if (lane >= o) v += u; }
            if (lane < 8) wsum[lane] = v;               // inclusive wave totals
        }
        __syncthreads();
        if (t < 512) {
            int b = t * 4;
            int ex = ((w == 0) ? 0 : wsum[w - 1]) + x - s4;
            int o0 = ex, o1 = ex + l0, o2 = o1 + l1, o3 = o2 + l2;
            off_[b] = o0; off_[b + 1] = o1; off_[b + 2] = o2; off_[b + 3] = o3;
            cnt[b] = o0; cnt[b + 1] = o1; cnt[b + 2] = o2; cnt[b + 3] = o3;   // scatter cursor
        }
        __syncthreads();
        for (int i = t; i < n; i += 1024) {
            int4 k = kp4[i];
            int c = (k.z >> CSH) * NCX + (k.w >> CSH);
            int pos = atomicAdd(&cnt[c], 1);   // within-cell order nondeterministic; consumers commutative
            int2 v; v.x = (k.z << 16) | k.w; v.y = __float_as_int(sc[i]);
            lppL[pos] = v;
            sidxL[pos] = (unsigned short)i;
        }
        __syncthreads();
        // pixel-max + rep (own index is min among same-pixel) per sorted slot; dump to global
        for (int j = t; j < n; j += 1024) {
            int2 v = lppL[j];
            int c = ((v.x >> 16) >> CSH) * NCX + ((v.x & 0xFFFF) >> CSH);
            int lo = off_[c], hi = cnt[c];     // cnt = end cursor after scatter
            int pmax = v.y; int myi = sidxL[j]; int rep = 1;
            for (int u = lo; u < hi; ++u) {
                int2 wv = lppL[u];
                if (wv.x == v.x) {
                    if (wv.y > pmax) pmax = wv.y;
                    if ((int)sidxL[u] < myi) rep = 0;
                }
            }
            pbr[j] = (int)(((unsigned)pmax & 0x7FFFFFFFu) | (rep ? 0x80000000u : 0u));
            ppk[j] = v;
            sidx[j] = myi;                     // own original index
        }
        for (int c = t; c < NC; c += 1024) { int2 g; g.x = off_[c]; g.y = cmx[c]; gcell[c] = g; }
        if (t == 0) { int2 g; g.x = n; g.y = 0; gcell[NC] = g; }
    } else {
        // correctness-only fallback (NC <= NCG): global scratch
        int* cntG = gscr; int* offG = gscr + NCG; int* cmxG = gscr + 2 * NCG;
        for (int i = t; i < NC; i += 1024) { cntG[i] = 0; cmxG[i] = 0; }
        __syncthreads();
        for (int i = t; i < n; i += 1024) {
            int4 k = kp4[i];
            int c = (k.z >> CSH) * NCX + (k.w >> CSH);
            atomicAdd(&cntG[c], 1);
            atomicMax(&cmxG[c], __float_as_int(sc[i]));
        }
        __syncthreads();
        if (t == 0) { int run = 0; for (int c = 0; c < NC; ++c) { offG[c] = run; run += cntG[c]; } }
        __syncthreads();
        for (int i = t; i < NC; i += 1024) cntG[i] = offG[i];
        __syncthreads();
        for (int i = t; i < n; i += 1024) {
            int4 k = kp4[i];
            int c = (k.z >> CSH) * NCX + (k.w >> CSH);
            int pos = atomicAdd(&cntG[c], 1);
            int2 v; v.x = (k.z << 16) | k.w; v.y = __float_as_int(sc[i]);
            ppk[pos] = v; sidx[pos] = i;
        }
        __syncthreads();
        for (int j = t; j < n; j += 1024) {
            int2 v = ppk[j];
            int c = ((v.x >> 16) >> CSH) * NCX + ((v.x & 0xFFFF) >> CSH);
            int lo = offG[c], hi = cntG[c];
            int pmax = v.y; int myi = sidx[j]; int rep = 1;
            for (int u = lo; u < hi; ++u) {
                int2 wv = ppk[u];
                if (wv.x == v.x) { if (wv.y > pmax) pmax = wv.y; if (sidx[u] < myi) rep = 0; }
            }
            pbr[j] = (int)(((unsigned)pmax & 0x7FFFFFFFu) | (rep ? 0x80000000u : 0u));
        }
        __syncthreads();
        for (int c = t; c < NC; c += 1024) { int2 g; g.x = offG[c]; g.y = cmxG[c]; gcell[c] = g; }
        if (t == 0) { int2 g; g.x = n; g.y = 0; gcell[NC] = g; }
    }
    if (t == 0) {
        int nret = nret_[0];
        int mx = rows > cols ? rows : cols;
        int nr1 = nret > 1 ? nret : 1;
        int dvs = (int)sqrt((double)n / (double)nr1);   // Python int() truncation
        if (dvs < 1) dvs = 1;
        int high = mx / dvs; if (high < 1) high = 1;
        // Adaptive RMAX (exact): if the packing bound at the first probe's radius r1 is
        // below kmin, high shrinks at probe 1 and no later probe exceeds r1.
        int kmin = (int)llround((double)nret * (1.0 - 0.1));
        int k1 = (1 + high) / 2;
        int r1 = k1 / 2;
        long long packb = (long long)((rows - 1) / (r1 + 1) + 1) *
                          (long long)((cols - 1) / (r1 + 1) + 1);
        int rmax = (packb < (long long)kmin) ? r1 : (high / 2);
        meta[0] = rmax;
        meta[1] = NCX;
        meta[2] = NCY;
    }
}

// ---------------- K2: query + fused finish (FENCE-FREE, atomics-only cross-block) ----------------
// Query: 16 thr/pt, cells+points in LDS (97.8 KB). dd via atomicExch, hist via atomicAdd.
// __syncthreads() drains the block's atomics (vmcnt(0) before barrier), then a ticket
// atomicAdd elects the last block, which re-reads hist/dd via atomic loads (atomicAdd(p,0))
// so no non-coherent cached copy can be observed. No __threadfence anywhere.
template<bool LDSP>
__global__ __launch_bounds__(TPB, 1) void query_finish_k(
    const int* __restrict__ kp, const float* __restrict__ sc,
    const int* __restrict__ nret_, const int* __restrict__ rows_, const int* __restrict__ cols_,
    const int* __restrict__ meta, int* __restrict__ done,
    const int2* __restrict__ gcell, const int2* __restrict__ ppk,
    const int* __restrict__ sidx, const int* __restrict__ pbr,
    int n, int* __restrict__ dd, int* __restrict__ hist,
    float* __restrict__ out) {
    __shared__ int2 lcell[NCLDS + 1];          // {off, maxbits}; reused as suf[] in finish
    __shared__ int2 lpp[LDSP ? QLP : 1];       // packed points {(y<<16)|x, score_bits}
    __shared__ int wsuf[8];
    __shared__ int wtK[10], wtN[10];
    __shared__ int ticket_s, rsh;
    int t = threadIdx.x, lane = t & 63, w = t >> 6;
    int RMAX = meta[0], NCX = meta[1], NCY = meta[2];
    int NC = NCX * NCY;
    int gt = blockIdx.x * TPB + t;
    int q = gt >> 4, sub = gt & 15;
    bool act = q < n;

    // prefetch per-point globals BEFORE staging barrier (latency hides under staging)
    int2 me; me.x = 0; me.y = 0;
    int idxv = 0, pbrv = 0, lo = 0, hi = 0, y = 0, x = 0, cy = 0, cx = 0;
    if (act) {
        me = ppk[q];
        idxv = sidx[q];
        pbrv = pbr[q];
        y = me.x >> 16; x = me.x & 0xFFFF;
        cy = y >> CSH;  cx = x >> CSH;
        int c0 = cy * NCX + cx;
        lo = gcell[c0].x; hi = gcell[c0 + 1].x;
    }
    bool cellsL = (NC <= NCLDS);
    if (cellsL) {
        for (int i = t; i <= NC; i += TPB) lcell[i] = gcell[i];
    }
    if constexpr (LDSP) {
        int nh = n >> 1;
        const int4* s4 = (const int4*)ppk;
        int4* d4 = (int4*)lpp;
        for (int i = t; i < nh; i += TPB) d4[i] = s4[i];
        if ((n & 1) && t == 0) lpp[n - 1] = ppk[n - 1];
    }
    __syncthreads();

    if (act) {
        const int2* P = LDSP ? (const int2*)lpp : ppk;
        const int2* C = cellsL ? (const int2*)lcell : gcell;
        int pb = pbrv & 0x7FFFFFFF;                // pixel-max score bits
        int d = RMAX + 1;                          // "no higher within RMAX" sentinel
        for (int j = lo + sub; j < hi; j += TPP) { // ring 0: own cell
            int2 v = P[j];
            if (v.y > pb) {
                int dy = y - (v.x >> 16);    dy = dy < 0 ? -dy : dy;
                int dx = x - (v.x & 0xFFFF); dx = dx < 0 ? -dx : dx;
                int c = dy > dx ? dy : dx;
                if (c < d) d = c;
            }
        }
        d = min(d, __shfl_xor(d, 1)); d = min(d, __shfl_xor(d, 2));
        d = min(d, __shfl_xor(d, 4)); d = min(d, __shfl_xor(d, 8));

        for (int R = 1;; ++R) {                    // expanding rings
            int LB = (R - 1) * CSZ + 1;            // min possible distance from ring-R cells
            if (LB >= d) break;                    // covers d == RMAX+1 cap too
            for (int e = sub; e < 8 * R; e += TPP) {
                int a, b;
                if (e < 2 * R + 1)      { a = -R; b = -R + e; }
                else if (e < 4 * R + 2) { a =  R; b = -R + (e - (2 * R + 1)); }
                else { int ss = e - (4 * R + 2); a = -R + 1 + (ss >> 1); b = (ss & 1) ? R : -R; }
                int ccy = cy + a, ccx = cx + b;
                if (ccy < 0 || ccy >= NCY || ccx < 0 || ccx >= NCX) continue;
                int cc = ccy * NCX + ccx;
                int2 cm = C[cc];                   // one ds_read_b64: {off, max}
                if (cm.y <= pb) continue;          // no strictly-greater score in this cell
                int jhi = C[cc + 1].x;
                for (int j = cm.x; j < jhi; ++j) {
                    int2 v = P[j];
                    if (v.y > pb) {
                        int dy = y - (v.x >> 16);    dy = dy < 0 ? -dy : dy;
                        int dx = x - (v.x & 0xFFFF); dx = dx < 0 ? -dx : dx;
                        int c = dy > dx ? dy : dx;
                        if (c < d) d = c;
                    }
                }
            }
            d = min(d, __shfl_xor(d, 1)); d = min(d, __shfl_xor(d, 2));
            d = min(d, __shfl_xor(d, 4)); d = min(d, __shfl_xor(d, 8));
        }
        if (sub == 0) {
            atomicExch(&dd[idxv], d);              // atomic write: device-coherent, fence-free
            int hb = d < HSIZE ? d : HSIZE - 1;    // packed: lo16 reps, hi16 points
            atomicAdd(&hist[hb], ((unsigned)pbrv >> 31) ? 0x10001 : 0x10000);
        }
    }

    // ---- completion election (no fences; syncthreads drains this block's atomics) ----
    __syncthreads();
    if (t == 0) ticket_s = atomicAdd(done, 1);
    __syncthreads();
    if (ticket_s != (int)gridDim.x - 1) return;

    // ---- finish phase (last block only, TPB=640 threads) ----
    int* suf = (int*)lcell;                        // [HSIZE+1] fits in 2*(NCLDS+1)
    int nret = nret_[0];

    // packed suffix sums of hist via atomic loads (512 threads x 4 buckets)
    int s0 = 0, s1 = 0, s2 = 0, s3 = 0, xv = 0;
    if (t < 512) {
        int bb = t * 4;
        int b0 = atomicAdd(&hist[bb], 0);
        int b1 = atomicAdd(&hist[bb + 1], 0);
        int b2 = atomicAdd(&hist[bb + 2], 0);
        int b3 = atomicAdd(&hist[bb + 3], 0);
        s3 = b3; s2 = b2 + s3; s1 = b1 + s2; s0 = b0 + s1;
        xv = s0;
        for (int o = 1; o < 64; o <<= 1) { int v = __shfl_down(xv, o); if (lane + o < 64) xv += v; }
        if (lane == 0) wsuf[w] = xv;               // w in 0..7
    }
    __syncthreads();
    if (w == 0) {
        int v = (lane < 8) ? wsuf[lane] : 0;
        for (int o = 1; o < 8; o <<= 1) { int u = __shfl_down(v, o); if (lane + o < 8) v += u; }
        if (lane < 8) wsuf[lane] = v;              // inclusive suffix of wave totals
    }
    __syncthreads();
    if (t < 512) {
        int S = xv + ((w < 7) ? wsuf[w + 1] : 0);  // suffix over all buckets >= 4t
        int after = S - s0;
        int bb = t * 4;
        suf[bb] = s0 + after; suf[bb + 1] = s1 + after;
        suf[bb + 2] = s2 + after; suf[bb + 3] = s3 + after;
    }
    if (t == 0) suf[HSIZE] = 0;
    __syncthreads();

    if (t == 0) {
        int rows = rows_[0], cols = cols_[0];
        int kmin = (int)llround((double)nret * (1.0 - 0.1));
        int kmax = (int)llround((double)nret * (1.0 + 0.1));
        int mx = rows > cols ? rows : cols;
        int nr1 = nret > 1 ? nret : 1;
        int dvs = (int)sqrt((double)n / (double)nr1);
        if (dvs < 1) dvs = 1;
        int high = mx / dvs; if (high < 1) high = 1;
        int low = 1, prev_k = -1, r_final = -1;
        bool found = false;
        while (true) {
            int k = (low + high) / 2;
            if (k == prev_k || low > high) break;
            int r = k / 2;                               // == k_odd // 2 for both parities
            int cnt = (r + 1 <= HSIZE) ? (suf[r + 1] & 0xFFFF) : 0;
            if (cnt >= kmin && cnt <= kmax) { r_final = r; found = true; break; }
            else if (cnt < kmin) high = k - 1;
            else low = k + 1;
            prev_k = k;
        }
        if (!found) {
            int kfb = prev_k > 0 ? prev_k : 1;
            r_final = kfb / 2;
        }
        rsh = r_final;
    }
    __syncthreads();
    int r = rsh;
    int m = (r + 1 <= HSIZE) ? (suf[r + 1] >> 16) : 0;   // total kept POINTS (hi16)

    // ordered selection: kept ascending, pad with non-kept ascending, truncate at nret
    unsigned long long lanemask = (lane == 0) ? 0ull : (~0ull >> (64 - lane));
    int runK = 0, runN = 0;
    for (int bb2 = 0; bb2 < n; bb2 += TPB) {
        int i = bb2 + t;
        bool valid = i < n;
        int dv = valid ? atomicAdd(&dd[i], 0) : 0;       // atomic load (coherent)
        bool f  = valid && (dv > r);
        bool nf = valid && !f;
        unsigned long long mk = __ballot(f);
        unsigned long long mn = __ballot(nf);
        int pk = __popcll(mk & lanemask);
        int pn = __popcll(mn & lanemask);
        if (lane == 0) { wtK[w] = __popcll(mk); wtN[w] = __popcll(mn); }
        __syncthreads();
        int exK = runK + pk, exN = runN + pn;
        for (int u = 0; u < w; ++u) { exK += wtK[u]; exN += wtN[u]; }
        int ctK = 0, ctN = 0;
        for (int u = 0; u < 10; ++u) { ctK += wtK[u]; ctN += wtN[u]; }
        __syncthreads();
        if (valid) {
            int slot = -1;
            if (f) {
                if (exK < nret) slot = exK;
            } else if (nf && m < nret && (m + exN) < nret) {
                slot = m + exN;
            }
            if (slot >= 0) {
                out[slot * 4 + 0] = (float)kp[i * 4 + 0];
                out[slot * 4 + 1] = (float)kp[i * 4 + 1];
                out[slot * 4 + 2] = (float)kp[i * 4 + 2];
                out[slot * 4 + 3] = (float)kp[i * 4 + 3];
                out[nret * 4 + slot] = sc[i];
            }
        }
        runK += ctK;
        runN += ctN;
    }
}

extern "C" void kernel_launch(void* const* d_in, const int* in_sizes, int n_in,
                              void* d_out, int out_size, void* d_ws, size_t ws_size,
                              hipStream_t stream) {
    const int*   kp   = (const int*)d_in[0];
    const float* sc   = (const float*)d_in[1];
    const int*   nret = (const int*)d_in[2];
    const int*   rows = (const int*)d_in[3];
    const int*   cols = (const int*)d_in[4];
    int n = in_sizes[1];                       // number of points

    int* hist   = (int*)d_ws;                  // 2048
    int* meta   = hist + HSIZE;                // 8
    int* done   = meta + 8;                    // 8
    int2* gcell = (int2*)(done + 8);           // NCG+16 int2 (even int offset -> 8B aligned)
    int* gscr   = (int*)(gcell + NCG + 16);    // 3*NCG (fallback scratch)
    int2* ppk   = (int2*)(gscr + 3 * NCG);     // n int2
    int* sidx   = (int*)(ppk + n);             // n
    int* pbr    = sidx + n;                    // n
    int* dd     = pbr + n;                     // n
    float* out  = (float*)d_out;

    build_k<<<1, 1024, 0, stream>>>(kp, sc, nret, rows, cols, n,
                                    hist, meta, done, gcell, ppk, sidx, pbr, gscr);
    int qblocks = (int)(((long long)n * TPP + TPB - 1) / TPB);   // 250 for n=10000
    if (n <= QLP)
        query_finish_k<true><<<qblocks, TPB, 0, stream>>>(kp, sc, nret, rows, cols,
                                                          meta, done, gcell, ppk, sidx, pbr,
                                                          n, dd, hist, out);
    else
        query_finish_k<false><<<qblocks, TPB, 0, stream>>>(kp, sc, nret, rows, cols,
                                                           meta, done, gcell, ppk, sidx, pbr,
                                                           n, dd, hist, out);
}

// Round 16
// 52.098 us; speedup vs baseline: 1.5038x; 1.5038x over previous
//
#include <hip/hip_runtime.h>

#define HSIZE 2048          // d-histogram buckets; packed lo16=pixel reps, hi16=points (n<32768)
#define CSH   6             // cell shift (64 px cells)
#define CSZ   64
#define NCG   4096          // global cell-array capacity
#define NCLDS 2048          // LDS cell capacity (this family: 34x60 = 2040)
#define BLP   10176         // build LDS point capacity
#define QLP   10176         // query LDS point capacity (81408 B)
#define TPP   16            // threads per point
#define TPB   640           // 40 pts/block -> 250 blocks (one round over 256 CUs)

// ---------------- K1: build (single workgroup) ----------------
// counting-sort points into cells (ppk/sidx); gcell = {off, maxbits} (+sentinel);
// pbr = pixelmax | rep<<31; meta = {RMAX, NCX, NCY}
__global__ __launch_bounds__(1024) void build_k(
    const int* __restrict__ kp, const float* __restrict__ sc,
    const int* __restrict__ nret_, const int* __restrict__ rows_, const int* __restrict__ cols_,
    int n, int* __restrict__ meta,
    int2* __restrict__ gcell, int2* __restrict__ ppk, int* __restrict__ sidx,
    int* __restrict__ pbr, int* __restrict__ gscr) {
    __shared__ int2 lppL[BLP];
    __shared__ unsigned short sidxL[BLP];
    __shared__ int cnt[NCLDS];
    __shared__ int off_[NCLDS];
    __shared__ int cmx[NCLDS];
    __shared__ int wsum[8];
    int t = threadIdx.x, lane = t & 63, w = t >> 6;
    int rows = rows_[0], cols = cols_[0];
    int NCX = (cols + CSZ - 1) >> CSH;
    int NCY = (rows + CSZ - 1) >> CSH;
    int NC = NCX * NCY;
    bool fits = (NC <= NCLDS) && (n <= BLP);
    const int4* kp4 = (const int4*)kp;

    if (fits) {
        for (int i = t; i < NCLDS; i += 1024) { cnt[i] = 0; cmx[i] = 0; }
        __syncthreads();
        for (int i = t; i < n; i += 1024) {
            int4 k = kp4[i];
            int c = (k.z >> CSH) * NCX + (k.w >> CSH);
            atomicAdd(&cnt[c], 1);
            atomicMax(&cmx[c], __float_as_int(sc[i]));   // scores > 0: bit order == value order
        }
        __syncthreads();
        // exclusive scan over NCLDS=2048: first 512 threads, 4 cells each, shfl scans
        int s4 = 0, l0 = 0, l1 = 0, l2 = 0, l3 = 0, x = 0;
        if (t < 512) {
            int b = t * 4;
            l0 = cnt[b]; l1 = cnt[b + 1]; l2 = cnt[b + 2]; l3 = cnt[b + 3];
            s4 = l0 + l1 + l2 + l3;
            x = s4;
            for (int o = 1; o < 64; o <<= 1) { int v = __shfl_up(x, o); if (lane >= o) x += v; }
            if (lane == 63) wsum[w] = x;
        }
        __syncthreads();
        if (w == 0) {
            int v = (lane < 8) ? wsum[lane] : 0;
            for (int o = 1; o < 8; o <<= 1) { int u = __shfl_up(v, o); if (lane >= o) v += u; }
            if (lane < 8) wsum[lane] = v;               // inclusive wave totals
        }
        __syncthreads();
        if (t < 512) {
            int b = t * 4;
            int ex = ((w == 0) ? 0 : wsum[w - 1]) + x - s4;
            int o0 = ex, o1 = ex + l0, o2 = o1 + l1, o3 = o2 + l2;
            off_[b] = o0; off_[b + 1] = o1; off_[b + 2] = o2; off_[b + 3] = o3;
            cnt[b] = o0; cnt[b + 1] = o1; cnt[b + 2] = o2; cnt[b + 3] = o3;   // scatter cursor
        }
        __syncthreads();
        for (int i = t; i < n; i += 1024) {
            int4 k = kp4[i];
            int c = (k.z >> CSH) * NCX + (k.w >> CSH);
            int pos = atomicAdd(&cnt[c], 1);   // within-cell order nondeterministic; consumers commutative
            int2 v; v.x = (k.z << 16) | k.w; v.y = __float_as_int(sc[i]);
            lppL[pos] = v;
            sidxL[pos] = (unsigned short)i;
        }
        __syncthreads();
        // pixel-max + rep (own index is min among same-pixel) per sorted slot; dump to global
        for (int j = t; j < n; j += 1024) {
            int2 v = lppL[j];
            int c = ((v.x >> 16) >> CSH) * NCX + ((v.x & 0xFFFF) >> CSH);
            int lo = off_[c], hi = cnt[c];     // cnt = end cursor after scatter
            int pmax = v.y; int myi = sidxL[j]; int rep = 1;
            for (int u = lo; u < hi; ++u) {
                int2 wv = lppL[u];
                if (wv.x == v.x) {
                    if (wv.y > pmax) pmax = wv.y;
                    if ((int)sidxL[u] < myi) rep = 0;
                }
            }
            pbr[j] = (int)(((unsigned)pmax & 0x7FFFFFFFu) | (rep ? 0x80000000u : 0u));
            ppk[j] = v;
            sidx[j] = myi;                     // own original index
        }
        for (int c = t; c < NC; c += 1024) { int2 g; g.x = off_[c]; g.y = cmx[c]; gcell[c] = g; }
        if (t == 0) { int2 g; g.x = n; g.y = 0; gcell[NC] = g; }
    } else {
        // correctness-only fallback (NC <= NCG): global scratch
        int* cntG = gscr; int* offG = gscr + NCG; int* cmxG = gscr + 2 * NCG;
        for (int i = t; i < NC; i += 1024) { cntG[i] = 0; cmxG[i] = 0; }
        __syncthreads();
        for (int i = t; i < n; i += 1024) {
            int4 k = kp4[i];
            int c = (k.z >> CSH) * NCX + (k.w >> CSH);
            atomicAdd(&cntG[c], 1);
            atomicMax(&cmxG[c], __float_as_int(sc[i]));
        }
        __syncthreads();
        if (t == 0) { int run = 0; for (int c = 0; c < NC; ++c) { offG[c] = run; run += cntG[c]; } }
        __syncthreads();
        for (int i = t; i < NC; i += 1024) cntG[i] = offG[i];
        __syncthreads();
        for (int i = t; i < n; i += 1024) {
            int4 k = kp4[i];
            int c = (k.z >> CSH) * NCX + (k.w >> CSH);
            int pos = atomicAdd(&cntG[c], 1);
            int2 v; v.x = (k.z << 16) | k.w; v.y = __float_as_int(sc[i]);
            ppk[pos] = v; sidx[pos] = i;
        }
        __syncthreads();
        for (int j = t; j < n; j += 1024) {
            int2 v = ppk[j];
            int c = ((v.x >> 16) >> CSH) * NCX + ((v.x & 0xFFFF) >> CSH);
            int lo = offG[c], hi = cntG[c];
            int pmax = v.y; int myi = sidx[j]; int rep = 1;
            for (int u = lo; u < hi; ++u) {
                int2 wv = ppk[u];
                if (wv.x == v.x) { if (wv.y > pmax) pmax = wv.y; if (sidx[u] < myi) rep = 0; }
            }
            pbr[j] = (int)(((unsigned)pmax & 0x7FFFFFFFu) | (rep ? 0x80000000u : 0u));
        }
        __syncthreads();
        for (int c = t; c < NC; c += 1024) { int2 g; g.x = offG[c]; g.y = cmxG[c]; gcell[c] = g; }
        if (t == 0) { int2 g; g.x = n; g.y = 0; gcell[NC] = g; }
    }
    if (t == 0) {
        int nret = nret_[0];
        int mx = rows > cols ? rows : cols;
        int nr1 = nret > 1 ? nret : 1;
        int dvs = (int)sqrt((double)n / (double)nr1);   // Python int() truncation
        if (dvs < 1) dvs = 1;
        int high = mx / dvs; if (high < 1) high = 1;
        // Adaptive RMAX (exact): if the packing bound at the first probe's radius r1 is
        // below kmin, high shrinks at probe 1 and no later probe exceeds r1.
        int kmin = (int)llround((double)nret * (1.0 - 0.1));
        int k1 = (1 + high) / 2;
        int r1 = k1 / 2;
        long long packb = (long long)((rows - 1) / (r1 + 1) + 1) *
                          (long long)((cols - 1) / (r1 + 1) + 1);
        int rmax = (packb < (long long)kmin) ? r1 : (high / 2);
        meta[0] = rmax;
        meta[1] = NCX;
        meta[2] = NCY;
    }
}

// ---------------- K2: query (16 thr/pt; cells AND points in LDS = 97.8 KB) ----------------
// NO global atomics: dd[i] = (d << 1) | rep  (plain store, single writer per point).
template<bool LDSP>
__global__ __launch_bounds__(TPB, 1) void query_k(
    const int* __restrict__ meta, const int2* __restrict__ gcell,
    const int2* __restrict__ ppk, const int* __restrict__ sidx,
    const int* __restrict__ pbr, int n, int* __restrict__ dd) {
    __shared__ int2 lcell[NCLDS + 1];          // {off, maxbits}
    __shared__ int2 lpp[LDSP ? QLP : 1];       // packed points {(y<<16)|x, score_bits}
    int t = threadIdx.x;
    int RMAX = meta[0], NCX = meta[1], NCY = meta[2];
    int NC = NCX * NCY;
    int gt = blockIdx.x * TPB + t;
    int q = gt >> 4, sub = gt & 15;
    bool act = q < n;

    // prefetch per-point globals BEFORE staging barrier (latency hides under staging)
    int2 me; me.x = 0; me.y = 0;
    int idxv = 0, pbrv = 0, lo = 0, hi = 0, y = 0, x = 0, cy = 0, cx = 0;
    if (act) {
        me = ppk[q];
        idxv = sidx[q];
        pbrv = pbr[q];
        y = me.x >> 16; x = me.x & 0xFFFF;
        cy = y >> CSH;  cx = x >> CSH;
        int c0 = cy * NCX + cx;
        lo = gcell[c0].x; hi = gcell[c0 + 1].x;
    }
    bool cellsL = (NC <= NCLDS);
    if (cellsL) {
        for (int i = t; i <= NC; i += TPB) lcell[i] = gcell[i];
    }
    if constexpr (LDSP) {
        int nh = n >> 1;
        const int4* s4 = (const int4*)ppk;
        int4* d4 = (int4*)lpp;
        for (int i = t; i < nh; i += TPB) d4[i] = s4[i];
        if ((n & 1) && t == 0) lpp[n - 1] = ppk[n - 1];
    }
    __syncthreads();

    if (act) {
        const int2* P = LDSP ? (const int2*)lpp : ppk;
        const int2* C = cellsL ? (const int2*)lcell : gcell;
        int pb = pbrv & 0x7FFFFFFF;                // pixel-max score bits
        int d = RMAX + 1;                          // "no higher within RMAX" sentinel
        for (int j = lo + sub; j < hi; j += TPP) { // ring 0: own cell
            int2 v = P[j];
            if (v.y > pb) {
                int dy = y - (v.x >> 16);    dy = dy < 0 ? -dy : dy;
                int dx = x - (v.x & 0xFFFF); dx = dx < 0 ? -dx : dx;
                int c = dy > dx ? dy : dx;
                if (c < d) d = c;
            }
        }
        d = min(d, __shfl_xor(d, 1)); d = min(d, __shfl_xor(d, 2));
        d = min(d, __shfl_xor(d, 4)); d = min(d, __shfl_xor(d, 8));

        for (int R = 1;; ++R) {                    // expanding rings
            int LB = (R - 1) * CSZ + 1;            // min possible distance from ring-R cells
            if (LB >= d) break;                    // covers d == RMAX+1 cap too
            for (int e = sub; e < 8 * R; e += TPP) {
                int a, b;
                if (e < 2 * R + 1)      { a = -R; b = -R + e; }
                else if (e < 4 * R + 2) { a =  R; b = -R + (e - (2 * R + 1)); }
                else { int ss = e - (4 * R + 2); a = -R + 1 + (ss >> 1); b = (ss & 1) ? R : -R; }
                int ccy = cy + a, ccx = cx + b;
                if (ccy < 0 || ccy >= NCY || ccx < 0 || ccx >= NCX) continue;
                int cc = ccy * NCX + ccx;
                int2 cm = C[cc];                   // one ds_read_b64: {off, max}
                if (cm.y <= pb) continue;          // no strictly-greater score in this cell
                int jhi = C[cc + 1].x;
                for (int j = cm.x; j < jhi; ++j) {
                    int2 v = P[j];
                    if (v.y > pb) {
                        int dy = y - (v.x >> 16);    dy = dy < 0 ? -dy : dy;
                        int dx = x - (v.x & 0xFFFF); dx = dx < 0 ? -dx : dx;
                        int c = dy > dx ? dy : dx;
                        if (c < d) d = c;
                    }
                }
            }
            d = min(d, __shfl_xor(d, 1)); d = min(d, __shfl_xor(d, 2));
            d = min(d, __shfl_xor(d, 4)); d = min(d, __shfl_xor(d, 8));
        }
        if (sub == 0)
            dd[idxv] = (d << 1) | (int)((unsigned)pbrv >> 31);   // plain store, no atomics
    }
}

// ---------------- K3: LDS histogram + binary-search replica + ordered select ----------------
__global__ __launch_bounds__(1024) void finish_k(
    const int* __restrict__ kp, const float* __restrict__ sc,
    const int* __restrict__ dd,
    const int* __restrict__ nret_, const int* __restrict__ rows_, const int* __restrict__ cols_,
    int n, float* __restrict__ out) {
    __shared__ int lhist[HSIZE];
    __shared__ int suf[HSIZE + 1];
    __shared__ int wsuf[16];
    __shared__ int wtK[16], wtN[16];
    __shared__ int rsh;
    int t = threadIdx.x, lane = t & 63, w = t >> 6;

    // build packed histogram from dd in LDS (lo16 = pixel reps, hi16 = points)
    lhist[t] = 0; lhist[t + 1024] = 0;
    __syncthreads();
    for (int i = t; i < n; i += 1024) {
        int dv = dd[i];
        int d = dv >> 1;
        int hb = d < HSIZE ? d : HSIZE - 1;
        atomicAdd(&lhist[hb], (dv & 1) ? 0x10001 : 0x10000);
    }
    __syncthreads();

    // packed suffix sums via shfl; no cross-carry: each component sum <= n < 32768
    int b0 = lhist[2 * t], b1 = lhist[2 * t + 1];
    int s = b0 + b1;
    int x = s;
    for (int o = 1; o < 64; o <<= 1) { int v = __shfl_down(x, o); if (lane + o < 64) x += v; }
    if (lane == 0) wsuf[w] = x;
    __syncthreads();
    if (w == 0) {
        int v = (lane < 16) ? wsuf[lane] : 0;
        for (int o = 1; o < 16; o <<= 1) { int u = __shfl_down(v, o); if (lane + o < 16) v += u; }
        if (lane < 16) wsuf[lane] = v;             // inclusive suffix of wave totals
    }
    __syncthreads();
    int S = x + ((w < 15) ? wsuf[w + 1] : 0);
    suf[2 * t] = S;
    suf[2 * t + 1] = S - b0;
    if (t == 0) suf[HSIZE] = 0;
    __syncthreads();

    if (t == 0) {
        int nret = nret_[0];
        int rows = rows_[0], cols = cols_[0];
        int kmin = (int)llround((double)nret * (1.0 - 0.1));
        int kmax = (int)llround((double)nret * (1.0 + 0.1));
        int mx = rows > cols ? rows : cols;
        int nr1 = nret > 1 ? nret : 1;
        int dvs = (int)sqrt((double)n / (double)nr1);
        if (dvs < 1) dvs = 1;
        int high = mx / dvs; if (high < 1) high = 1;
        int low = 1, prev_k = -1, r_final = -1;
        bool found = false;
        while (true) {
            int k = (low + high) / 2;
            if (k == prev_k || low > high) break;
            int r = k / 2;                               // == k_odd // 2 for both parities
            int cnt = (r + 1 <= HSIZE) ? (suf[r + 1] & 0xFFFF) : 0;
            if (cnt >= kmin && cnt <= kmax) { r_final = r; found = true; break; }
            else if (cnt < kmin) high = k - 1;
            else low = k + 1;
            prev_k = k;
        }
        if (!found) {
            int kfb = prev_k > 0 ? prev_k : 1;
            r_final = kfb / 2;
        }
        rsh = r_final;
    }
    __syncthreads();
    int r = rsh;
    int nret = nret_[0];
    int m = (r + 1 <= HSIZE) ? (suf[r + 1] >> 16) : 0;   // total kept POINTS (hi16)

    // ordered selection: kept ascending, pad with non-kept ascending, truncate at nret
    unsigned long long lanemask = (lane == 0) ? 0ull : (~0ull >> (64 - lane));
    int runK = 0, runN = 0;
    for (int bb = 0; bb < n; bb += 1024) {
        int i = bb + t;
        bool valid = i < n;
        bool f  = valid && ((dd[i] >> 1) > r);
        bool nf = valid && !f;
        unsigned long long mk = __ballot(f);
        unsigned long long mn = __ballot(nf);
        int pk = __popcll(mk & lanemask);
        int pn = __popcll(mn & lanemask);
        if (lane == 0) { wtK[w] = __popcll(mk); wtN[w] = __popcll(mn); }
        __syncthreads();
        int exK = runK + pk, exN = runN + pn;
        for (int u = 0; u < w; ++u) { exK += wtK[u]; exN += wtN[u]; }
        int ctK = 0, ctN = 0;
        for (int u = 0; u < 16; ++u) { ctK += wtK[u]; ctN += wtN[u]; }
        __syncthreads();
        if (valid) {
            int slot = -1;
            if (f) {
                if (exK < nret) slot = exK;
            } else if (nf && m < nret && (m + exN) < nret) {
                slot = m + exN;
            }
            if (slot >= 0) {
                out[slot * 4 + 0] = (float)kp[i * 4 + 0];
                out[slot * 4 + 1] = (float)kp[i * 4 + 1];
                out[slot * 4 + 2] = (float)kp[i * 4 + 2];
                out[slot * 4 + 3] = (float)kp[i * 4 + 3];
                out[nret * 4 + slot] = sc[i];
            }
        }
        runK += ctK;
        runN += ctN;
    }
}

extern "C" void kernel_launch(void* const* d_in, const int* in_sizes, int n_in,
                              void* d_out, int out_size, void* d_ws, size_t ws_size,
                              hipStream_t stream) {
    const int*   kp   = (const int*)d_in[0];
    const float* sc   = (const float*)d_in[1];
    const int*   nret = (const int*)d_in[2];
    const int*   rows = (const int*)d_in[3];
    const int*   cols = (const int*)d_in[4];
    int n = in_sizes[1];                       // number of points

    int* meta   = (int*)d_ws;                  // 16
    int2* gcell = (int2*)(meta + 16);          // NCG+16 int2 (even int offset -> 8B aligned)
    int* gscr   = (int*)(gcell + NCG + 16);    // 3*NCG (fallback scratch)
    int2* ppk   = (int2*)(gscr + 3 * NCG);     // n int2
    int* sidx   = (int*)(ppk + n);             // n
    int* pbr    = sidx + n;                    // n
    int* dd     = pbr + n;                     // n
    float* out  = (float*)d_out;

    build_k<<<1, 1024, 0, stream>>>(kp, sc, nret, rows, cols, n,
                                    meta, gcell, ppk, sidx, pbr, gscr);
    int qblocks = (int)(((long long)n * TPP + TPB - 1) / TPB);   // 250 for n=10000
    if (n <= QLP)
        query_k<true><<<qblocks, TPB, 0, stream>>>(meta, gcell, ppk, sidx, pbr, n, dd);
    else
        query_k<false><<<qblocks, TPB, 0, stream>>>(meta, gcell, ppk, sidx, pbr, n, dd);
    finish_k<<<1, 1024, 0, stream>>>(kp, sc, dd, nret, rows, cols, n, out);
}